// Round 7
// baseline (473.909 us; speedup 1.0000x reference)
//
#include <hip/hip_runtime.h>

// Problem constants
#define BB 16
#define NN 1024
#define FIN 64
#define FOUT 128
#define DD 64
#define HH 4
#define NEG 0.2f

#define RT 32     // rows per block in K1
#define RT2 16    // rows per block in K2
#define CT 128    // column tile in K2
#define MLDS 1032 // padded maskL row stride (shorts)

typedef __attribute__((ext_vector_type(8))) short short8;
typedef __attribute__((ext_vector_type(4))) float f32x4;

__device__ __forceinline__ unsigned short f2bf(float x) {
    union { float f; unsigned u; } v; v.f = x;
    unsigned r = v.u + 0x7fffu + ((v.u >> 16) & 1u);
    return (unsigned short)(r >> 16);
}
__device__ __forceinline__ float bf2f(unsigned short s) {
    union { float f; unsigned u; } v; v.u = ((unsigned)s) << 16;
    return v.f;
}
__device__ __forceinline__ unsigned pack2bf(float lo, float hi) {
    return (unsigned)f2bf(lo) | ((unsigned)f2bf(hi) << 16);
}

#define MFMA(a, b, c) __builtin_amdgcn_mfma_f32_16x16x32_bf16((a), (b), (c), 0, 0, 0)

// ---------------- Kernel 1: h_prime (bf16 fragment-packed), attn_src/dst (bf16 hi/lo), hp_sum ----------------
__global__ __launch_bounds__(256) void gat_k1(
    const float* __restrict__ h,      // [B,N,FIN]
    const float* __restrict__ w,      // [H,FIN,FOUT]
    const float* __restrict__ a_src,  // [H,FOUT,DD]
    const float* __restrict__ a_dst,  // [H,FOUT,DD]
    unsigned short* __restrict__ asHg,  // [B,H,N,DD] bf16 hi
    unsigned short* __restrict__ asLg,  // lo
    unsigned short* __restrict__ adHg,
    unsigned short* __restrict__ adLg,
    unsigned short* __restrict__ hpPg,  // [B*H][N/32][FOUT][32] bf16 fragment-packed h'
    float* __restrict__ hpsum)          // [B,N,FOUT]
{
    __shared__ float hL[RT][FIN + 1];      // 32x65
    __shared__ float wL[FIN][FOUT + 2];    // 64x130
    __shared__ float hpL[RT][FOUT + 2];    // 32x130

    const int t  = threadIdx.x;
    const int tx = t & 31;
    const int ty = t >> 5;           // 0..7
    const int blk = blockIdx.x;
    const int b   = blk / (NN / RT);
    const int n0  = (blk % (NN / RT)) * RT;

    for (int idx = t; idx < RT * FIN / 4; idx += 256) {
        int r = (idx * 4) / FIN;
        int f = (idx * 4) % FIN;
        float4 v = *reinterpret_cast<const float4*>(&h[((size_t)b * NN + n0 + r) * FIN + f]);
        hL[r][f + 0] = v.x; hL[r][f + 1] = v.y; hL[r][f + 2] = v.z; hL[r][f + 3] = v.w;
    }

    float sum_acc[4][4];
#pragma unroll
    for (int i = 0; i < 4; i++)
#pragma unroll
        for (int j = 0; j < 4; j++) sum_acc[i][j] = 0.f;

    for (int hh = 0; hh < HH; ++hh) {
        __syncthreads();
        for (int idx = t; idx < FIN * FOUT / 4; idx += 256) {
            int k = (idx * 4) / FOUT;
            int o = (idx * 4) % FOUT;
            float4 v = *reinterpret_cast<const float4*>(&w[((size_t)hh * FIN + k) * FOUT + o]);
            wL[k][o + 0] = v.x; wL[k][o + 1] = v.y; wL[k][o + 2] = v.z; wL[k][o + 3] = v.w;
        }
        __syncthreads();

        float acc[4][4];
#pragma unroll
        for (int i = 0; i < 4; i++)
#pragma unroll
            for (int j = 0; j < 4; j++) acc[i][j] = 0.f;

#pragma unroll 8
        for (int k = 0; k < FIN; k++) {
            float av0 = hL[ty][k], av1 = hL[ty + 8][k], av2 = hL[ty + 16][k], av3 = hL[ty + 24][k];
            float bv0 = wL[k][tx], bv1 = wL[k][tx + 32], bv2 = wL[k][tx + 64], bv3 = wL[k][tx + 96];
            acc[0][0] += av0 * bv0; acc[0][1] += av0 * bv1; acc[0][2] += av0 * bv2; acc[0][3] += av0 * bv3;
            acc[1][0] += av1 * bv0; acc[1][1] += av1 * bv1; acc[1][2] += av1 * bv2; acc[1][3] += av1 * bv3;
            acc[2][0] += av2 * bv0; acc[2][1] += av2 * bv1; acc[2][2] += av2 * bv2; acc[2][3] += av2 * bv3;
            acc[3][0] += av3 * bv0; acc[3][1] += av3 * bv1; acc[3][2] += av3 * bv2; acc[3][3] += av3 * bv3;
        }

        const size_t bh = (size_t)b * HH + hh;
#pragma unroll
        for (int i = 0; i < 4; i++) {
            int r = i * 8 + ty;
#pragma unroll
            for (int j = 0; j < 4; j++) {
                int o = j * 32 + tx;
                hpL[r][o] = acc[i][j];
                sum_acc[i][j] += acc[i][j];
            }
        }
        __syncthreads();

        float as0[4], as1[4], ad0[4], ad1[4];
#pragma unroll
        for (int i = 0; i < 4; i++) { as0[i] = 0.f; as1[i] = 0.f; ad0[i] = 0.f; ad1[i] = 0.f; }

#pragma unroll 4
        for (int o = 0; o < FOUT; o++) {
            size_t aoff = ((size_t)hh * FOUT + o) * DD;
            float sv0 = a_src[aoff + tx];
            float sv1 = a_src[aoff + tx + 32];
            float dv0 = a_dst[aoff + tx];
            float dv1 = a_dst[aoff + tx + 32];
#pragma unroll
            for (int i = 0; i < 4; i++) {
                float hv = hpL[i * 8 + ty][o];
                as0[i] += hv * sv0; as1[i] += hv * sv1;
                ad0[i] += hv * dv0; ad1[i] += hv * dv1;
            }
        }
#pragma unroll
        for (int i = 0; i < 4; i++) {
            int r = i * 8 + ty;
            size_t base = (bh * NN + n0 + r) * DD;
            unsigned short h0, h1;
            h0 = f2bf(as0[i]); asHg[base + tx]      = h0; asLg[base + tx]      = f2bf(as0[i] - bf2f(h0));
            h1 = f2bf(as1[i]); asHg[base + tx + 32] = h1; asLg[base + tx + 32] = f2bf(as1[i] - bf2f(h1));
            h0 = f2bf(ad0[i]); adHg[base + tx]      = h0; adLg[base + tx]      = f2bf(ad0[i] - bf2f(h0));
            h1 = f2bf(ad1[i]); adHg[base + tx + 32] = h1; adLg[base + tx + 32] = f2bf(ad1[i] - bf2f(h1));
        }

        // fragment-packed bf16 h' : hpP[bh][n0/32][o][r]
        {
            int o = t & 127, half = t >> 7;
            size_t dst = ((bh * (NN / 32) + (n0 >> 5)) * FOUT + o) * 32 + half * 16;
            short8 v0, v1;
#pragma unroll
            for (int k = 0; k < 8; k++) v0[k] = (short)f2bf(hpL[half * 16 + k][o]);
#pragma unroll
            for (int k = 0; k < 8; k++) v1[k] = (short)f2bf(hpL[half * 16 + 8 + k][o]);
            *reinterpret_cast<short8*>(&hpPg[dst])     = v0;
            *reinterpret_cast<short8*>(&hpPg[dst + 8]) = v1;
        }
    }

#pragma unroll
    for (int i = 0; i < 4; i++) {
        int r = i * 8 + ty;
        size_t rowoff = ((size_t)b * NN + n0 + r) * FOUT;
#pragma unroll
        for (int j = 0; j < 4; j++) {
            hpsum[rowoff + j * 32 + tx] = sum_acc[i][j];
        }
    }
}

// ---------------- Kernel 2: swapped-MFMA scores (row-local), barrier-free passes ----------------
// grid: BB*(NN/RT2) = 1024 blocks, 256 threads (4 waves). 2 blocks/CU, VGPR budget 256.
__global__ __launch_bounds__(256)
__attribute__((amdgpu_waves_per_eu(2, 2)))
void gat_k2(
    const float* __restrict__ mask,   // [B,1,N,N]
    const float* __restrict__ bias,   // [FOUT]
    const unsigned short* __restrict__ asHg,
    const unsigned short* __restrict__ asLg,
    const unsigned short* __restrict__ adHg,
    const unsigned short* __restrict__ adLg,
    const unsigned short* __restrict__ hpPg,  // [B*H][N/32][FOUT][32]
    const float* __restrict__ hpsum,  // [B,N,FOUT]
    float* __restrict__ out,          // [B,N,FOUT]
    float* __restrict__ attn)         // [B,H,N,N]
{
    // smem: maskL (16 x MLDS bf16 = 33,024 B) | red at +33,792 (512 B)
    // epilogue aliases the front as outLW (64 x 132 f32 = 33,792 B)
    __shared__ __align__(16) unsigned char smem[33792 + 512];
    unsigned short* maskL = reinterpret_cast<unsigned short*>(smem);
    float2*         red   = reinterpret_cast<float2*>(smem + 33792);

    const int t  = threadIdx.x;
    const int l  = t & 63;
    const int w  = t >> 6;
    const int li = l & 15;
    const int g  = l >> 4;

    // XCD-aware bijective swizzle (1024 % 8 == 0)
    const int lb = (blockIdx.x & 7) * 128 + (blockIdx.x >> 3);
    const int b  = lb >> 6;
    const int n0 = (lb & 63) * RT2;

    f32x4 oacc[8];
#pragma unroll
    for (int of = 0; of < 8; of++) oacc[of] = f32x4{0.f, 0.f, 0.f, 0.f};

    const int colb = w * 32;  // this wave's 32-col strip base within a 128-tile

    for (int hh = 0; hh < HH; hh++) {
        const size_t bh = (size_t)b * HH + hh;

        // as fragments (Y operand): lane supplies as[r = n0+li][k = ks*32 + g*8 ..+8]
        short8 aH[2], aL[2];
#pragma unroll
        for (int ks = 0; ks < 2; ks++) {
            size_t src = (bh * NN + n0 + li) * DD + ks * 32 + g * 8;
            aH[ks] = *reinterpret_cast<const short8*>(&asHg[src]);
            aL[ks] = *reinterpret_cast<const short8*>(&asLg[src]);
        }

        const unsigned short* adHb = adHg + bh * NN * DD;
        const unsigned short* adLb = adLg + bh * NN * DD;
        const unsigned short* hpb  = hpPg + bh * (size_t)(NN / 32) * FOUT * 32;

        // ===== pass A: S^T = MFMA(ad, as); lane (li,g) gets S[r=li][c=colb+cf*16+g*4+q]
        float sc[8][2][4];
        short8 xH[2][2][2], xL[2][2][2];   // [buf][cf][ks]

#define LOADX(BUF, CTV)                                                                  \
        {                                                                                \
            _Pragma("unroll")                                                            \
            for (int cf = 0; cf < 2; cf++)                                               \
            _Pragma("unroll")                                                            \
            for (int ks = 0; ks < 2; ks++) {                                             \
                size_t off = (size_t)((CTV) * CT + colb + cf * 16 + li) * DD             \
                           + ks * 32 + g * 8;                                            \
                xH[BUF][cf][ks] = *reinterpret_cast<const short8*>(&adHb[off]);          \
                xL[BUF][cf][ks] = *reinterpret_cast<const short8*>(&adLb[off]);          \
            }                                                                            \
        }

        LOADX(0, 0)
#pragma unroll
        for (int ct = 0; ct < 8; ct++) {
            const int cb = ct & 1;
            if (ct < 7) {
                if (cb == 0) { LOADX(1, ct + 1) } else { LOADX(0, ct + 1) }
            }
#pragma unroll
            for (int cf = 0; cf < 2; cf++) {
                f32x4 s = f32x4{0.f, 0.f, 0.f, 0.f};
                __builtin_amdgcn_s_setprio(1);
#pragma unroll
                for (int ks = 0; ks < 2; ks++) {
                    s = MFMA(xH[cb][cf][ks], aH[ks], s);
                    s = MFMA(xH[cb][cf][ks], aL[ks], s);
                    s = MFMA(xL[cb][cf][ks], aH[ks], s);
                }
                __builtin_amdgcn_s_setprio(0);
#pragma unroll
                for (int q = 0; q < 4; q++) {
                    float v = s[q];
                    sc[ct][cf][q] = v > 0.f ? v : NEG * v;
                }
            }
        }
#undef LOADX

        // ===== softmax stats: per-lane over own 64, xor-16/32 across g, LDS across waves
        float m = -3.0e38f, lv = 0.f;
#pragma unroll
        for (int ct = 0; ct < 8; ct++)
#pragma unroll
            for (int cf = 0; cf < 2; cf++)
#pragma unroll
                for (int q = 0; q < 4; q++)
                    m = fmaxf(m, sc[ct][cf][q]);
#pragma unroll
        for (int ct = 0; ct < 8; ct++)
#pragma unroll
            for (int cf = 0; cf < 2; cf++)
#pragma unroll
                for (int q = 0; q < 4; q++)
                    lv += __expf(sc[ct][cf][q] - m);
#pragma unroll
        for (int msk = 16; msk <= 32; msk <<= 1) {
            float om = __shfl_xor(m, msk);
            float ol = __shfl_xor(lv, msk);
            float nm = fmaxf(m, om);
            lv = lv * __expf(m - nm) + ol * __expf(om - nm);
            m = nm;
        }
        __syncthreads();
        if (g == 0) red[w * 16 + li] = make_float2(m, lv);
        __syncthreads();
        float mf, linv;
        {
            float2 r0 = red[li], r1 = red[16 + li], r2 = red[32 + li], r3 = red[48 + li];
            mf = fmaxf(fmaxf(r0.x, r1.x), fmaxf(r2.x, r3.x));
            float ls = r0.y * __expf(r0.x - mf) + r1.y * __expf(r1.x - mf)
                     + r2.y * __expf(r2.x - mf) + r3.y * __expf(r3.x - mf);
            linv = 1.0f / ls;
        }

        // ===== pass B: p -> attn (float4) -> in-register pa -> PV. ZERO barriers.
#pragma unroll
        for (int ct = 0; ct < 8; ct++) {
            float mvv[2][4];
            if (hh == 0) {
#pragma unroll
                for (int cf = 0; cf < 2; cf++) {
                    int c = ct * CT + colb + cf * 16 + g * 4;
                    float4 mv = *reinterpret_cast<const float4*>(
                        &mask[((size_t)b * NN + n0 + li) * NN + c]);
                    mvv[cf][0] = mv.x; mvv[cf][1] = mv.y; mvv[cf][2] = mv.z; mvv[cf][3] = mv.w;
                    uint2 mw;
                    mw.x = pack2bf(mv.x, mv.y);
                    mw.y = pack2bf(mv.z, mv.w);
                    *reinterpret_cast<uint2*>(&maskL[li * MLDS + c]) = mw;
                }
            } else {
#pragma unroll
                for (int cf = 0; cf < 2; cf++) {
                    int c = ct * CT + colb + cf * 16 + g * 4;
                    uint2 mw = *reinterpret_cast<const uint2*>(&maskL[li * MLDS + c]);
                    mvv[cf][0] = bf2f((unsigned short)(mw.x & 0xffff));
                    mvv[cf][1] = bf2f((unsigned short)(mw.x >> 16));
                    mvv[cf][2] = bf2f((unsigned short)(mw.y & 0xffff));
                    mvv[cf][3] = bf2f((unsigned short)(mw.y >> 16));
                }
            }

            unsigned pk[4];
#pragma unroll
            for (int cf = 0; cf < 2; cf++) {
                float p0 = __expf(sc[ct][cf][0] - mf) * linv * mvv[cf][0];
                float p1 = __expf(sc[ct][cf][1] - mf) * linv * mvv[cf][1];
                float p2 = __expf(sc[ct][cf][2] - mf) * linv * mvv[cf][2];
                float p3 = __expf(sc[ct][cf][3] - mf) * linv * mvv[cf][3];
                float4 av; av.x = p0; av.y = p1; av.z = p2; av.w = p3;
                *reinterpret_cast<float4*>(
                    &attn[(bh * NN + n0 + li) * NN + ct * CT + colb + cf * 16 + g * 4]) = av;
                pk[cf * 2 + 0] = pack2bf(p0, p1);
                pk[cf * 2 + 1] = pack2bf(p2, p3);
            }

            // assemble pa: lane (li,g) needs P[li][colb + g*8 + j], j=0..7
            int s0l = li + ((g & 1) << 5);
            int s1l = s0l + 16;
            unsigned A0 = (unsigned)__shfl((int)pk[0], s0l);
            unsigned A1 = (unsigned)__shfl((int)pk[1], s0l);
            unsigned A2 = (unsigned)__shfl((int)pk[2], s0l);
            unsigned A3 = (unsigned)__shfl((int)pk[3], s0l);
            unsigned B0 = (unsigned)__shfl((int)pk[0], s1l);
            unsigned B1 = (unsigned)__shfl((int)pk[1], s1l);
            unsigned B2 = (unsigned)__shfl((int)pk[2], s1l);
            unsigned B3 = (unsigned)__shfl((int)pk[3], s1l);
            bool hi = (g >= 2);
            union { unsigned u[4]; short8 v; } pa;
            pa.u[0] = hi ? A2 : A0;
            pa.u[1] = hi ? A3 : A1;
            pa.u[2] = hi ? B2 : B0;
            pa.u[3] = hi ? B3 : B1;

            // PV partial over this wave's c-strip: all 128 o columns
            const unsigned short* hp_ct = hpb + (size_t)(4 * ct + w) * FOUT * 32;
            __builtin_amdgcn_s_setprio(1);
#pragma unroll
            for (int of = 0; of < 8; of++) {
                short8 hb = *reinterpret_cast<const short8*>(
                    &hp_ct[(size_t)(of * 16 + li) * 32 + g * 8]);
                oacc[of] = MFMA(pa.v, hb, oacc[of]);
            }
            __builtin_amdgcn_s_setprio(0);
        }
    }

    // ===== final: 4-way cross-wave reduction of oacc, then epilogue
    __syncthreads();  // maskL no longer needed; all pass-B LDS traffic done
    float* outLW = reinterpret_cast<float*>(smem);   // [64 rows][132]
#pragma unroll
    for (int of = 0; of < 8; of++)
#pragma unroll
        for (int q = 0; q < 4; q++)
            outLW[(w * 16 + g * 4 + q) * 132 + of * 16 + li] = oacc[of][q];
    __syncthreads();
    {
        int r  = t >> 4;
        int ob = (t & 15) * 8;
        float acc8[8];
#pragma unroll
        for (int k = 0; k < 8; k++) acc8[k] = 0.f;
#pragma unroll
        for (int ww = 0; ww < 4; ww++)
#pragma unroll
            for (int k = 0; k < 8; k++)
                acc8[k] += outLW[(ww * 16 + r) * 132 + ob + k];
        size_t obase = ((size_t)b * NN + n0 + r) * FOUT + ob;
#pragma unroll
        for (int k4 = 0; k4 < 2; k4++) {
            float4 bs = *reinterpret_cast<const float4*>(&bias[ob + k4 * 4]);
            float4 hs = *reinterpret_cast<const float4*>(&hpsum[obase + k4 * 4]);
            float4 v;
            v.x = acc8[k4 * 4 + 0] + bs.x + hs.x;
            v.y = acc8[k4 * 4 + 1] + bs.y + hs.y;
            v.z = acc8[k4 * 4 + 2] + bs.z + hs.z;
            v.w = acc8[k4 * 4 + 3] + bs.w + hs.w;
            *reinterpret_cast<float4*>(&out[obase + k4 * 4]) = v;
        }
    }
}

extern "C" void kernel_launch(void* const* d_in, const int* in_sizes, int n_in,
                              void* d_out, int out_size, void* d_ws, size_t ws_size,
                              hipStream_t stream) {
    const float* h      = (const float*)d_in[0];
    const float* mask   = (const float*)d_in[1];
    const float* w      = (const float*)d_in[2];
    const float* a_src  = (const float*)d_in[3];
    const float* a_dst  = (const float*)d_in[4];
    const float* bias   = (const float*)d_in[5];

    float* out  = (float*)d_out;                          // [B,N,FOUT]
    float* attn = out + (size_t)BB * NN * FOUT;           // [B,H,N,N]

    const size_t NASD = (size_t)BB * HH * NN * DD;        // 4M elems
    unsigned short* asHg = (unsigned short*)d_ws;
    unsigned short* asLg = asHg + NASD;
    unsigned short* adHg = asLg + NASD;
    unsigned short* adLg = adHg + NASD;
    unsigned short* hpPg = adLg + NASD;                   // B*H*FOUT*N = 8M elems
    float* hpsum = (float*)(hpPg + (size_t)BB * HH * FOUT * NN);

    dim3 block(256);
    gat_k1<<<dim3(BB * (NN / RT)),  block, 0, stream>>>(h, w, a_src, a_dst, asHg, asLg, adHg, adLg, hpPg, hpsum);
    gat_k2<<<dim3(BB * (NN / RT2)), block, 0, stream>>>(mask, bias, asHg, asLg, adHg, adLg, hpPg, hpsum, out, attn);
}

// Round 8
// 387.294 us; speedup vs baseline: 1.2236x; 1.2236x over previous
//
#include <hip/hip_runtime.h>

// Problem constants
#define BB 16
#define NN 1024
#define FIN 64
#define FOUT 128
#define DD 64
#define HH 4
#define NEG 0.2f

#define RT 32     // rows per block in K1
#define RT2 16    // rows per block in K2
#define CT 128    // column tile in K2

typedef __attribute__((ext_vector_type(8))) short short8;
typedef __attribute__((ext_vector_type(4))) float f32x4;

__device__ __forceinline__ unsigned short f2bf(float x) {
    union { float f; unsigned u; } v; v.f = x;
    unsigned r = v.u + 0x7fffu + ((v.u >> 16) & 1u);
    return (unsigned short)(r >> 16);
}
__device__ __forceinline__ float bf2f(unsigned short s) {
    union { float f; unsigned u; } v; v.u = ((unsigned)s) << 16;
    return v.f;
}

#define MFMA(a, b, c) __builtin_amdgcn_mfma_f32_16x16x32_bf16((a), (b), (c), 0, 0, 0)

// ---------------- Kernel 1: h_prime (bf16 fragment-packed), attn_src/dst (bf16 hi/lo), hp_sum ----------------
__global__ __launch_bounds__(256) void gat_k1(
    const float* __restrict__ h,      // [B,N,FIN]
    const float* __restrict__ w,      // [H,FIN,FOUT]
    const float* __restrict__ a_src,  // [H,FOUT,DD]
    const float* __restrict__ a_dst,  // [H,FOUT,DD]
    unsigned short* __restrict__ asHg,  // [B,H,N,DD] bf16 hi
    unsigned short* __restrict__ asLg,  // lo
    unsigned short* __restrict__ adHg,
    unsigned short* __restrict__ adLg,
    unsigned short* __restrict__ hpPg,  // [B*H][N/32][FOUT][32] bf16 fragment-packed h'
    float* __restrict__ hpsum)          // [B,N,FOUT]
{
    __shared__ float hL[RT][FIN + 1];      // 32x65
    __shared__ float wL[FIN][FOUT + 2];    // 64x130
    __shared__ float hpL[RT][FOUT + 2];    // 32x130

    const int t  = threadIdx.x;
    const int tx = t & 31;
    const int ty = t >> 5;           // 0..7
    const int blk = blockIdx.x;
    const int b   = blk / (NN / RT);
    const int n0  = (blk % (NN / RT)) * RT;

    for (int idx = t; idx < RT * FIN / 4; idx += 256) {
        int r = (idx * 4) / FIN;
        int f = (idx * 4) % FIN;
        float4 v = *reinterpret_cast<const float4*>(&h[((size_t)b * NN + n0 + r) * FIN + f]);
        hL[r][f + 0] = v.x; hL[r][f + 1] = v.y; hL[r][f + 2] = v.z; hL[r][f + 3] = v.w;
    }

    float sum_acc[4][4];
#pragma unroll
    for (int i = 0; i < 4; i++)
#pragma unroll
        for (int j = 0; j < 4; j++) sum_acc[i][j] = 0.f;

    for (int hh = 0; hh < HH; ++hh) {
        __syncthreads();
        for (int idx = t; idx < FIN * FOUT / 4; idx += 256) {
            int k = (idx * 4) / FOUT;
            int o = (idx * 4) % FOUT;
            float4 v = *reinterpret_cast<const float4*>(&w[((size_t)hh * FIN + k) * FOUT + o]);
            wL[k][o + 0] = v.x; wL[k][o + 1] = v.y; wL[k][o + 2] = v.z; wL[k][o + 3] = v.w;
        }
        __syncthreads();

        float acc[4][4];
#pragma unroll
        for (int i = 0; i < 4; i++)
#pragma unroll
            for (int j = 0; j < 4; j++) acc[i][j] = 0.f;

#pragma unroll 8
        for (int k = 0; k < FIN; k++) {
            float av0 = hL[ty][k], av1 = hL[ty + 8][k], av2 = hL[ty + 16][k], av3 = hL[ty + 24][k];
            float bv0 = wL[k][tx], bv1 = wL[k][tx + 32], bv2 = wL[k][tx + 64], bv3 = wL[k][tx + 96];
            acc[0][0] += av0 * bv0; acc[0][1] += av0 * bv1; acc[0][2] += av0 * bv2; acc[0][3] += av0 * bv3;
            acc[1][0] += av1 * bv0; acc[1][1] += av1 * bv1; acc[1][2] += av1 * bv2; acc[1][3] += av1 * bv3;
            acc[2][0] += av2 * bv0; acc[2][1] += av2 * bv1; acc[2][2] += av2 * bv2; acc[2][3] += av2 * bv3;
            acc[3][0] += av3 * bv0; acc[3][1] += av3 * bv1; acc[3][2] += av3 * bv2; acc[3][3] += av3 * bv3;
        }

        const size_t bh = (size_t)b * HH + hh;
#pragma unroll
        for (int i = 0; i < 4; i++) {
            int r = i * 8 + ty;
#pragma unroll
            for (int j = 0; j < 4; j++) {
                int o = j * 32 + tx;
                hpL[r][o] = acc[i][j];
                sum_acc[i][j] += acc[i][j];
            }
        }
        __syncthreads();

        float as0[4], as1[4], ad0[4], ad1[4];
#pragma unroll
        for (int i = 0; i < 4; i++) { as0[i] = 0.f; as1[i] = 0.f; ad0[i] = 0.f; ad1[i] = 0.f; }

#pragma unroll 4
        for (int o = 0; o < FOUT; o++) {
            size_t aoff = ((size_t)hh * FOUT + o) * DD;
            float sv0 = a_src[aoff + tx];
            float sv1 = a_src[aoff + tx + 32];
            float dv0 = a_dst[aoff + tx];
            float dv1 = a_dst[aoff + tx + 32];
#pragma unroll
            for (int i = 0; i < 4; i++) {
                float hv = hpL[i * 8 + ty][o];
                as0[i] += hv * sv0; as1[i] += hv * sv1;
                ad0[i] += hv * dv0; ad1[i] += hv * dv1;
            }
        }
#pragma unroll
        for (int i = 0; i < 4; i++) {
            int r = i * 8 + ty;
            size_t base = (bh * NN + n0 + r) * DD;
            unsigned short h0, h1;
            h0 = f2bf(as0[i]); asHg[base + tx]      = h0; asLg[base + tx]      = f2bf(as0[i] - bf2f(h0));
            h1 = f2bf(as1[i]); asHg[base + tx + 32] = h1; asLg[base + tx + 32] = f2bf(as1[i] - bf2f(h1));
            h0 = f2bf(ad0[i]); adHg[base + tx]      = h0; adLg[base + tx]      = f2bf(ad0[i] - bf2f(h0));
            h1 = f2bf(ad1[i]); adHg[base + tx + 32] = h1; adLg[base + tx + 32] = f2bf(ad1[i] - bf2f(h1));
        }

        // fragment-packed bf16 h' : hpP[bh][n0/32][o][r]
        {
            int o = t & 127, half = t >> 7;
            size_t dst = ((bh * (NN / 32) + (n0 >> 5)) * FOUT + o) * 32 + half * 16;
            short8 v0, v1;
#pragma unroll
            for (int k = 0; k < 8; k++) v0[k] = (short)f2bf(hpL[half * 16 + k][o]);
#pragma unroll
            for (int k = 0; k < 8; k++) v1[k] = (short)f2bf(hpL[half * 16 + 8 + k][o]);
            *reinterpret_cast<short8*>(&hpPg[dst])     = v0;
            *reinterpret_cast<short8*>(&hpPg[dst + 8]) = v1;
        }
    }

#pragma unroll
    for (int i = 0; i < 4; i++) {
        int r = i * 8 + ty;
        size_t rowoff = ((size_t)b * NN + n0 + r) * FOUT;
#pragma unroll
        for (int j = 0; j < 4; j++) {
            hpsum[rowoff + j * 32 + tx] = sum_acc[i][j];
        }
    }
}

// ---------------- Kernel 2: MFMA scores (reg-cached) -> single-exp softmax -> attn + PV ----------------
// grid: BB*(NN/RT2) = 1024 blocks, 256 threads (4 waves). LDS 8.7 KB -> 4 blocks/CU.
__global__ __launch_bounds__(256) void gat_k2(
    const float* __restrict__ mask,   // [B,1,N,N]
    const float* __restrict__ bias,   // [FOUT]
    const unsigned short* __restrict__ asHg,
    const unsigned short* __restrict__ asLg,
    const unsigned short* __restrict__ adHg,
    const unsigned short* __restrict__ adLg,
    const unsigned short* __restrict__ hpPg,  // [B*H][N/32][FOUT][32]
    const float* __restrict__ hpsum,  // [B,N,FOUT]
    float* __restrict__ out,          // [B,N,FOUT]
    float* __restrict__ attn)         // [B,H,N,N]
{
    __shared__ __align__(16) unsigned char smem[8192 + 512];
    unsigned short* pBs0 = reinterpret_cast<unsigned short*>(smem);          // 4 KB
    unsigned short* pBs1 = reinterpret_cast<unsigned short*>(smem + 4096);   // 4 KB
    float*          redm = reinterpret_cast<float*>(smem + 8192);            // 64 f32
    float*          redl = reinterpret_cast<float*>(smem + 8192 + 256);      // 64 f32
    float*          outL = reinterpret_cast<float*>(smem);                   // epilogue alias, 8 KB

    const int t  = threadIdx.x;
    const int l  = t & 63;
    const int w  = t >> 6;
    const int li = l & 15;
    const int g  = l >> 4;

    // XCD-aware bijective swizzle (1024 % 8 == 0)
    const int lb = (blockIdx.x & 7) * 128 + (blockIdx.x >> 3);
    const int b  = lb >> 6;
    const int n0 = (lb & 63) * RT2;

    f32x4 oacc[2];
    oacc[0] = f32x4{0.f, 0.f, 0.f, 0.f};
    oacc[1] = f32x4{0.f, 0.f, 0.f, 0.f};

    for (int hh = 0; hh < HH; hh++) {
        const size_t bh = (size_t)b * HH + hh;

        // A fragments (as rows n0+li, k = ks*32 + g*8)
        short8 aH[2], aL[2];
#pragma unroll
        for (int ks = 0; ks < 2; ks++) {
            size_t src = (bh * NN + n0 + li) * DD + ks * 32 + g * 8;
            aH[ks] = *reinterpret_cast<const short8*>(&asHg[src]);
            aL[ks] = *reinterpret_cast<const short8*>(&asLg[src]);
        }

        const unsigned short* adHb = adHg + bh * NN * DD;
        const unsigned short* adLb = adLg + bh * NN * DD;

        // ===== pass A: scores -> register cache (lrelu'd) =====
        float sc[8][2][4];
#pragma unroll
        for (int ct = 0; ct < 8; ct++) {
#pragma unroll
            for (int cf = 0; cf < 2; cf++) {
                short8 bHr[2], bLr[2];
#pragma unroll
                for (int ks = 0; ks < 2; ks++) {
                    size_t off = (size_t)(ct * CT + w * 32 + cf * 16 + li) * DD + ks * 32 + g * 8;
                    bHr[ks] = *reinterpret_cast<const short8*>(&adHb[off]);
                    bLr[ks] = *reinterpret_cast<const short8*>(&adLb[off]);
                }
                f32x4 s = f32x4{0.f, 0.f, 0.f, 0.f};
                __builtin_amdgcn_s_setprio(1);
#pragma unroll
                for (int ks = 0; ks < 2; ks++) {
                    s = MFMA(aH[ks], bHr[ks], s);
                    s = MFMA(aH[ks], bLr[ks], s);
                    s = MFMA(aL[ks], bHr[ks], s);
                }
                __builtin_amdgcn_s_setprio(0);
#pragma unroll
                for (int q = 0; q < 4; q++) {
                    float v = s[q];
                    sc[ct][cf][q] = v > 0.f ? v : NEG * v;
                }
            }
        }

        // ===== softmax, single-exp =====
        // (1) row max, no exp
        float mreg[4];
#pragma unroll
        for (int q = 0; q < 4; q++) {
            float m = sc[0][0][q];
#pragma unroll
            for (int ct = 0; ct < 8; ct++)
                m = fmaxf(m, fmaxf(sc[ct][0][q], sc[ct][1][q]));
#pragma unroll
            for (int msk = 1; msk < 16; msk <<= 1)
                m = fmaxf(m, __shfl_xor(m, msk));
            mreg[q] = m;
        }
        __syncthreads();   // red region free (prev head done)
        if (li == 0) {
#pragma unroll
            for (int q = 0; q < 4; q++) redm[w * 16 + g * 4 + q] = mreg[q];
        }
        __syncthreads();
        float mf[4];
#pragma unroll
        for (int q = 0; q < 4; q++) {
            int row = g * 4 + q;
            mf[q] = fmaxf(fmaxf(redm[row], redm[16 + row]),
                          fmaxf(redm[32 + row], redm[48 + row]));
        }
        // (2) e-pass: overwrite sc with exp(sc-mf), accumulate l
        float lreg[4] = {0.f, 0.f, 0.f, 0.f};
#pragma unroll
        for (int ct = 0; ct < 8; ct++)
#pragma unroll
            for (int cf = 0; cf < 2; cf++)
#pragma unroll
                for (int q = 0; q < 4; q++) {
                    float e = __expf(sc[ct][cf][q] - mf[q]);
                    sc[ct][cf][q] = e;
                    lreg[q] += e;
                }
#pragma unroll
        for (int q = 0; q < 4; q++) {
#pragma unroll
            for (int msk = 1; msk < 16; msk <<= 1)
                lreg[q] += __shfl_xor(lreg[q], msk);
        }
        if (li == 0) {
#pragma unroll
            for (int q = 0; q < 4; q++) redl[w * 16 + g * 4 + q] = lreg[q];
        }
        __syncthreads();
        float linv[4];
#pragma unroll
        for (int q = 0; q < 4; q++) {
            int row = g * 4 + q;
            linv[q] = 1.0f / (redl[row] + redl[16 + row] + redl[32 + row] + redl[48 + row]);
        }

        // ===== pass B: p = e*linv*mask -> attn store -> pB transpose -> PV =====
        const unsigned short* hpbase = hpPg + bh * (size_t)(NN / 32) * FOUT * 32;
#pragma unroll
        for (int ct = 0; ct < 8; ct++) {
            // mask loads (issued early; L3-resident, 64B-coalesced per 16 li lanes)
            float mvv[2][4];
#pragma unroll
            for (int cf = 0; cf < 2; cf++)
#pragma unroll
                for (int q = 0; q < 4; q++)
                    mvv[cf][q] = mask[((size_t)b * NN + n0 + g * 4 + q) * NN
                                      + ct * CT + w * 32 + cf * 16 + li];

            unsigned short* pB = (ct & 1) ? pBs1 : pBs0;
            float pm[2][4];
#pragma unroll
            for (int cf = 0; cf < 2; cf++)
#pragma unroll
                for (int q = 0; q < 4; q++) {
                    int row = g * 4 + q;
                    int cl  = w * 32 + cf * 16 + li;
                    float pmv = sc[ct][cf][q] * linv[q] * mvv[cf][q];
                    attn[(bh * NN + n0 + row) * NN + ct * CT + cl] = pmv;
                    pm[cf][q] = pmv;
                }
#pragma unroll
            for (int cf = 0; cf < 2; cf++)
#pragma unroll
                for (int q = 0; q < 4; q++) {
                    int row = g * 4 + q;
                    int cl  = w * 32 + cf * 16 + li;
                    pB[row * 128 + (cl ^ (row * 8))] = f2bf(pm[cf][q]);
                }

            // T14: issue PV B-operand loads BEFORE the barrier; drain only LDS writes
            const unsigned short* hpb = hpbase + (size_t)ct * 4 * FOUT * 32;
            short8 hbv[4][2];
#pragma unroll
            for (int kc = 0; kc < 4; kc++) {
                hbv[kc][0] = *reinterpret_cast<const short8*>(
                    &hpb[((size_t)kc * FOUT + w * 32 + li) * 32 + g * 8]);
                hbv[kc][1] = *reinterpret_cast<const short8*>(
                    &hpb[((size_t)kc * FOUT + w * 32 + 16 + li) * 32 + g * 8]);
            }
            asm volatile("s_waitcnt lgkmcnt(0)\n\ts_barrier" ::: "memory");

#pragma unroll
            for (int kc = 0; kc < 4; kc++) {
                int k = kc * 32 + g * 8;
                short8 pa = *reinterpret_cast<const short8*>(&pB[li * 128 + (k ^ (li * 8))]);
                __builtin_amdgcn_s_setprio(1);
                oacc[0] = MFMA(pa, hbv[kc][0], oacc[0]);
                oacc[1] = MFMA(pa, hbv[kc][1], oacc[1]);
                __builtin_amdgcn_s_setprio(0);
            }
        }
    }

    // epilogue: stage oacc -> LDS (f32 16x128), then coalesced out write
    __syncthreads();
#pragma unroll
    for (int of = 0; of < 2; of++)
#pragma unroll
        for (int q = 0; q < 4; q++) {
            int row = g * 4 + q;
            int col = w * 32 + of * 16 + li;
            outL[row * 128 + col] = oacc[of][q];
        }
    __syncthreads();
    {
        int row = t >> 4, cb = (t & 15) * 8;
        size_t obase = ((size_t)b * NN + n0 + row) * FOUT + cb;
#pragma unroll
        for (int k4 = 0; k4 < 2; k4++) {
            float4 v  = *reinterpret_cast<float4*>(&outL[row * 128 + cb + k4 * 4]);
            float4 bs = *reinterpret_cast<const float4*>(&bias[cb + k4 * 4]);
            float4 hs = *reinterpret_cast<const float4*>(&hpsum[obase + k4 * 4]);
            v.x += bs.x + hs.x; v.y += bs.y + hs.y; v.z += bs.z + hs.z; v.w += bs.w + hs.w;
            *reinterpret_cast<float4*>(&out[obase + k4 * 4]) = v;
        }
    }
}

extern "C" void kernel_launch(void* const* d_in, const int* in_sizes, int n_in,
                              void* d_out, int out_size, void* d_ws, size_t ws_size,
                              hipStream_t stream) {
    const float* h      = (const float*)d_in[0];
    const float* mask   = (const float*)d_in[1];
    const float* w      = (const float*)d_in[2];
    const float* a_src  = (const float*)d_in[3];
    const float* a_dst  = (const float*)d_in[4];
    const float* bias   = (const float*)d_in[5];

    float* out  = (float*)d_out;                          // [B,N,FOUT]
    float* attn = out + (size_t)BB * NN * FOUT;           // [B,H,N,N]

    const size_t NASD = (size_t)BB * HH * NN * DD;        // 4M elems
    unsigned short* asHg = (unsigned short*)d_ws;
    unsigned short* asLg = asHg + NASD;
    unsigned short* adHg = asLg + NASD;
    unsigned short* adLg = adHg + NASD;
    unsigned short* hpPg = adLg + NASD;                   // B*H*FOUT*N = 8M elems
    float* hpsum = (float*)(hpPg + (size_t)BB * HH * FOUT * NN);

    dim3 block(256);
    gat_k1<<<dim3(BB * (NN / RT)),  block, 0, stream>>>(h, w, a_src, a_dst, asHg, asLg, adHg, adLg, hpPg, hpsum);
    gat_k2<<<dim3(BB * (NN / RT2)), block, 0, stream>>>(mask, bias, asHg, asLg, adHg, adLg, hpPg, hpsum, out, attn);
}